// Round 1
// baseline (661.113 us; speedup 1.0000x reference)
//
#include <hip/hip_runtime.h>
#include <hip/hip_bf16.h>

#define B_ 64
#define T_ 512
#define LOG2E 1.4426950408889634f

__device__ __forceinline__ float fast_exp2(float x){ return __builtin_amdgcn_exp2f(x); }
__device__ __forceinline__ float fast_rcp(float x){ return __builtin_amdgcn_rcpf(x); }
__device__ __forceinline__ float sigmoidf_(float x){ return fast_rcp(1.0f + fast_exp2(-x*LOG2E)); }

// ---------------- Kernel 1: P1[t][j][b] = proj of x (k*log2e, 0.1*v, 0.1*sigmoid(g)) ----
__global__ __launch_bounds__(256) void k_proj1(const float* __restrict__ X,
    const float* __restrict__ Wk, const float* __restrict__ bk,
    const float* __restrict__ Ww, const float* __restrict__ bw,
    const float* __restrict__ Wg, const float* __restrict__ bg,
    float* __restrict__ P1)
{
  __shared__ __align__(16) float A[64*132];
  __shared__ float Wc[128*12];
  __shared__ float bb[9];
  int tid = threadIdx.x;
  long r0 = (long)blockIdx.x * 64;
  const float4* X4 = (const float4*)(X + r0*128);
  #pragma unroll
  for (int it=0; it<8; ++it){
    int f4 = tid + it*256;
    float4 v = X4[f4];
    int f = f4*4; int row = f>>7; int k = f&127;
    A[row*132+k]   = v.x; A[row*132+k+1] = v.y;
    A[row*132+k+2] = v.z; A[row*132+k+3] = v.w;
  }
  #pragma unroll
  for (int it=0; it<5; ++it){
    int w = tid + it*256;
    if (w < 1152){
      int k = w/9, j = w%9;
      float val;
      if (j<3) val = Wk[k*3+j]; else if (j<6) val = Ww[k*3+j-3]; else val = Wg[k*3+j-6];
      Wc[k*12+j] = val;
    }
  }
  if (tid < 9){
    float v; if (tid<3) v = bk[tid]; else if (tid<6) v = bw[tid-3]; else v = bg[tid-6];
    bb[tid] = v;
  }
  __syncthreads();
  for (int o = tid; o < 576; o += 256){
    int row = o/9, j = o%9;
    float acc = bb[j];
    #pragma unroll 8
    for (int k=0;k<128;++k) acc = fmaf(A[row*132+k], Wc[k*12+j], acc);
    if (j<3) acc *= LOG2E;
    else if (j<6) acc *= 0.1f;
    else acc = 0.1f * sigmoidf_(acc);
    long r = r0 + row;
    int b = (int)(r >> 9); int t = (int)(r & 511);
    P1[(t*9+j)*64 + b] = acc;
  }
}

// ---------------- scan core: one lane = one batch element, 24-float memory in regs ------
template<int STORE_ALL>
__device__ __forceinline__ void scan_core(const float* __restrict__ P,
                                          float* __restrict__ Rout, int lane)
{
  float m[24];
  #pragma unroll
  for (int i=0;i<24;++i) m[i]=0.f;
  float p[9];
  #pragma unroll
  for (int j=0;j<9;++j) p[j] = P[j*64+lane];
  for (int t=0;t<T_;++t){
    const float* Pn = P + (long)((t<T_-1)?(t+1):t)*576;
    float pn[9];
    #pragma unroll
    for (int j=0;j<9;++j) pn[j] = Pn[j*64+lane];
    float k0=p[0],k1=p[1],k2=p[2];
    float s[8];
    #pragma unroll
    for (int n=0;n<8;++n)
      s[n] = fmaf(m[n*3+2],k2, fmaf(m[n*3+1],k1, m[n*3]*k0));
    float mx = fmaxf(fmaxf(fmaxf(s[0],s[1]),fmaxf(s[2],s[3])),
                     fmaxf(fmaxf(s[4],s[5]),fmaxf(s[6],s[7])));
    float pe[8]; float S = 0.f;
    #pragma unroll
    for (int n=0;n<8;++n){ pe[n] = fast_exp2(s[n]-mx); S += pe[n]; }
    float rinv = fast_rcp(S);
    float w[8];
    #pragma unroll
    for (int n=0;n<8;++n) w[n] = pe[n]*rinv;
    if (STORE_ALL || t == T_-1){
      #pragma unroll
      for (int d=0; d<3; ++d){
        float rd = 0.f;
        #pragma unroll
        for (int n=0;n<8;++n) rd = fmaf(w[n], m[n*3+d], rd);
        if (STORE_ALL) Rout[(t*3+d)*64 + lane] = rd;
        else           Rout[d*64 + lane] = rd;
      }
    }
    float v0=p[3],v1=p[4],v2=p[5], e0=p[6],e1=p[7],e2=p[8];
    // mem = mem + w_n * (0.1*v_d - 0.1*e_d*mem)   (0.1 pre-folded into v,e)
    #pragma unroll
    for (int n=0;n<8;++n){
      m[n*3]   = fmaf(w[n], fmaf(-e0, m[n*3],   v0), m[n*3]);
      m[n*3+1] = fmaf(w[n], fmaf(-e1, m[n*3+1], v1), m[n*3+1]);
      m[n*3+2] = fmaf(w[n], fmaf(-e2, m[n*3+2], v2), m[n*3+2]);
    }
    #pragma unroll
    for (int j=0;j<9;++j) p[j]=pn[j];
  }
}

__global__ __launch_bounds__(64) void k_scan1(const float* __restrict__ P1,
                                              float* __restrict__ R1)
{
  scan_core<1>(P1, R1, (int)threadIdx.x);
}

// ---------------- Kernel 3: fused z1=x@W1o, o1=sigmoid(z1+b+read*Wr), P2=o1@W2kwg -------
__global__ __launch_bounds__(256) void k_fused(const float* __restrict__ X,
    const float* __restrict__ W1o, const float* __restrict__ b1o,
    const float* __restrict__ R1,
    const float* __restrict__ W2k, const float* __restrict__ b2k,
    const float* __restrict__ W2w, const float* __restrict__ b2w,
    const float* __restrict__ W2g, const float* __restrict__ b2g,
    float* __restrict__ P2, float* __restrict__ O1last)
{
  __shared__ __align__(16) float At[128*20];   // transposed A tile [k][row], pad 16->20
  __shared__ __align__(16) float o1t[16*516];  // o1 tile [row][col], pad 512->516
  __shared__ float wrS[3*512];
  __shared__ float b1S[512];
  __shared__ float rdS[48];
  int tid = threadIdx.x;
  long r0 = (long)blockIdx.x * 16;
  int b = (int)(r0 >> 9); int t0 = (int)(r0 & 511);
  const float4* X4 = (const float4*)(X + r0*128);
  #pragma unroll
  for (int it=0; it<2; ++it){
    int f4 = tid + it*256;
    float4 v = X4[f4];
    int f = f4*4; int row = f>>7; int k = f&127;
    At[(k  )*20+row] = v.x;
    At[(k+1)*20+row] = v.y;
    At[(k+2)*20+row] = v.z;
    At[(k+3)*20+row] = v.w;
  }
  #pragma unroll
  for (int it=0; it<6; ++it){
    int f = tid + it*256; // 1536 read-part weights W1o[128..130][:]
    wrS[f] = W1o[(128 + (f>>9))*512 + (f&511)];
  }
  b1S[tid] = b1o[tid]; b1S[tid+256] = b1o[tid+256];
  if (tid < 48){
    int i = tid/3, d = tid%3;
    rdS[tid] = R1[((t0+i)*3+d)*64 + b];
  }
  __syncthreads();
  int c0 = tid, c1 = tid+256;
  float acc0[16], acc1[16];
  #pragma unroll
  for (int r=0;r<16;++r){acc0[r]=0.f;acc1[r]=0.f;}
  #pragma unroll 4
  for (int k=0;k<128;++k){
    float w0 = W1o[k*512 + c0];
    float w1 = W1o[k*512 + c1];
    const float4* a4 = (const float4*)(At + k*20);
    float av[16]; float4 q;
    q = a4[0]; av[0]=q.x; av[1]=q.y; av[2]=q.z; av[3]=q.w;
    q = a4[1]; av[4]=q.x; av[5]=q.y; av[6]=q.z; av[7]=q.w;
    q = a4[2]; av[8]=q.x; av[9]=q.y; av[10]=q.z; av[11]=q.w;
    q = a4[3]; av[12]=q.x; av[13]=q.y; av[14]=q.z; av[15]=q.w;
    #pragma unroll
    for (int r=0;r<16;++r){
      acc0[r] = fmaf(av[r], w0, acc0[r]);
      acc1[r] = fmaf(av[r], w1, acc1[r]);
    }
  }
  #pragma unroll
  for (int r=0;r<16;++r){
    float add0 = b1S[c0] + rdS[r*3]*wrS[c0] + rdS[r*3+1]*wrS[512+c0] + rdS[r*3+2]*wrS[1024+c0];
    float add1 = b1S[c1] + rdS[r*3]*wrS[c1] + rdS[r*3+1]*wrS[512+c1] + rdS[r*3+2]*wrS[1024+c1];
    o1t[r*516+c0] = sigmoidf_(acc0[r]+add0);
    o1t[r*516+c1] = sigmoidf_(acc1[r]+add1);
  }
  __syncthreads();
  if (tid < 144){
    int r = tid/9, j = tid%9;
    const float* W2x; float bias; int jj;
    if (j<3){ W2x=W2k; jj=j;   bias=b2k[jj]; }
    else if (j<6){ W2x=W2w; jj=j-3; bias=b2w[jj]; }
    else { W2x=W2g; jj=j-6; bias=b2g[jj]; }
    float acc = bias;
    #pragma unroll 8
    for (int c=0;c<512;++c) acc = fmaf(o1t[r*516+c], W2x[c*3+jj], acc);
    if (j<3) acc *= LOG2E;
    else if (j<6) acc *= 0.1f;
    else acc = 0.1f*sigmoidf_(acc);
    P2[((long)(t0+r)*9+j)*64 + b] = acc;
  }
  if (t0 == 496){
    O1last[b*512 + tid]       = o1t[15*516 + tid];
    O1last[b*512 + tid + 256] = o1t[15*516 + tid + 256];
  }
}

// ---------------- Kernel 4: block0 = scan2 (final read only); blocks 1..64 = Opart ------
__global__ __launch_bounds__(128) void k_scan2_opart(const float* __restrict__ P2,
    float* __restrict__ R2F,
    const float* __restrict__ O1last, const float* __restrict__ W2o,
    const float* __restrict__ b2o, float* __restrict__ Opart)
{
  if (blockIdx.x == 0){
    if (threadIdx.x < 64) scan_core<0>(P2, R2F, (int)threadIdx.x);
    return;
  }
  __shared__ __align__(16) float s[512];
  int b = blockIdx.x - 1; int tid = threadIdx.x;
  float4 v = ((const float4*)(O1last + b*512))[tid];
  ((float4*)s)[tid] = v;
  __syncthreads();
  float acc = b2o[tid];
  #pragma unroll 8
  for (int n=0;n<512;++n) acc = fmaf(s[n], W2o[n*128+tid], acc);
  Opart[b*128+tid] = acc;
}

// ---------------- Kernel 5: out = sigmoid(Opart + read2 @ W2o[512:515]) -----------------
__global__ __launch_bounds__(256) void k_final(const float* __restrict__ Opart,
    const float* __restrict__ R2F, const float* __restrict__ W2o,
    float* __restrict__ out)
{
  int idx = blockIdx.x*256 + threadIdx.x;
  if (idx < 8192){
    int b = idx >> 7; int o = idx & 127;
    float r0 = R2F[b], r1 = R2F[64+b], r2 = R2F[128+b];
    float v = Opart[idx]
            + r0*W2o[512*128+o] + r1*W2o[513*128+o] + r2*W2o[514*128+o];
    out[idx] = sigmoidf_(v);
  }
}

extern "C" void kernel_launch(void* const* d_in, const int* in_sizes, int n_in,
                              void* d_out, int out_size, void* d_ws, size_t ws_size,
                              hipStream_t stream)
{
  const float* X  = (const float*)d_in[0];
  const float* W1k= (const float*)d_in[1]; const float* b1k=(const float*)d_in[2];
  const float* W1w= (const float*)d_in[3]; const float* b1w=(const float*)d_in[4];
  const float* W1g= (const float*)d_in[5]; const float* b1g=(const float*)d_in[6];
  const float* W1o= (const float*)d_in[7]; const float* b1o=(const float*)d_in[8];
  const float* W2k= (const float*)d_in[9]; const float* b2k=(const float*)d_in[10];
  const float* W2w= (const float*)d_in[11]; const float* b2w=(const float*)d_in[12];
  const float* W2g= (const float*)d_in[13]; const float* b2g=(const float*)d_in[14];
  const float* W2o= (const float*)d_in[15]; const float* b2o=(const float*)d_in[16];

  float* ws = (float*)d_ws;
  float* P1     = ws;               // 512*9*64   = 294912
  float* R1     = P1 + 294912;      // 512*3*64   =  98304
  float* P2     = R1 + 98304;       // 512*9*64   = 294912
  float* O1last = P2 + 294912;      // 64*512     =  32768
  float* R2F    = O1last + 32768;   // 3*64       =    192
  float* Opart  = R2F + 192;        // 64*128     =   8192
  float* out    = (float*)d_out;

  hipLaunchKernelGGL(k_proj1, dim3(512), dim3(256), 0, stream,
                     X, W1k,b1k, W1w,b1w, W1g,b1g, P1);
  hipLaunchKernelGGL(k_scan1, dim3(1), dim3(64), 0, stream, P1, R1);
  hipLaunchKernelGGL(k_fused, dim3(2048), dim3(256), 0, stream,
                     X, W1o, b1o, R1, W2k,b2k, W2w,b2w, W2g,b2g, P2, O1last);
  hipLaunchKernelGGL(k_scan2_opart, dim3(65), dim3(128), 0, stream,
                     P2, R2F, O1last, W2o, b2o, Opart);
  hipLaunchKernelGGL(k_final, dim3(32), dim3(256), 0, stream,
                     Opart, R2F, W2o, out);
}

// Round 2
// 610.204 us; speedup vs baseline: 1.0834x; 1.0834x over previous
//
#include <hip/hip_runtime.h>
#include <hip/hip_bf16.h>

#define B_ 64
#define T_ 512
#define LOG2E 1.4426950408889634f

__device__ __forceinline__ float fast_exp2(float x){ return __builtin_amdgcn_exp2f(x); }
__device__ __forceinline__ float fast_rcp(float x){ return __builtin_amdgcn_rcpf(x); }
__device__ __forceinline__ float sigmoidf_(float x){ return fast_rcp(1.0f + fast_exp2(-x*LOG2E)); }

// ---------------- Kernel 1: P1[t][j][b] = proj of x (k*log2e, 0.1*v, 0.1*sigmoid(g)) ----
__global__ __launch_bounds__(256) void k_proj1(const float* __restrict__ X,
    const float* __restrict__ Wk, const float* __restrict__ bk,
    const float* __restrict__ Ww, const float* __restrict__ bw,
    const float* __restrict__ Wg, const float* __restrict__ bg,
    float* __restrict__ P1)
{
  __shared__ __align__(16) float A[64*132];
  __shared__ float Wc[128*12];
  __shared__ float bb[9];
  int tid = threadIdx.x;
  long r0 = (long)blockIdx.x * 64;
  const float4* X4 = (const float4*)(X + r0*128);
  #pragma unroll
  for (int it=0; it<8; ++it){
    int f4 = tid + it*256;
    float4 v = X4[f4];
    int f = f4*4; int row = f>>7; int k = f&127;
    A[row*132+k]   = v.x; A[row*132+k+1] = v.y;
    A[row*132+k+2] = v.z; A[row*132+k+3] = v.w;
  }
  #pragma unroll
  for (int it=0; it<5; ++it){
    int w = tid + it*256;
    if (w < 1152){
      int k = w/9, j = w%9;
      float val;
      if (j<3) val = Wk[k*3+j]; else if (j<6) val = Ww[k*3+j-3]; else val = Wg[k*3+j-6];
      Wc[k*12+j] = val;
    }
  }
  if (tid < 9){
    float v; if (tid<3) v = bk[tid]; else if (tid<6) v = bw[tid-3]; else v = bg[tid-6];
    bb[tid] = v;
  }
  __syncthreads();
  for (int o = tid; o < 576; o += 256){
    int row = o/9, j = o%9;
    float acc = bb[j];
    #pragma unroll 8
    for (int k=0;k<128;++k) acc = fmaf(A[row*132+k], Wc[k*12+j], acc);
    if (j<3) acc *= LOG2E;
    else if (j<6) acc *= 0.1f;
    else acc = 0.1f * sigmoidf_(acc);
    long r = r0 + row;
    int b = (int)(r >> 9); int t = (int)(r & 511);
    P1[(t*9+j)*64 + b] = acc;
  }
}

// ---------------- scan core: one lane = one batch element, 24-float memory in regs ------
// One step: scores -> exp2 (no max-sub; scores bounded << 127) -> tree-sum -> rcp
// -> read = (sum pe*m)*rinv (overlaps rcp latency) -> gated write update.
// Prefetch of p for step t+2 is issued AFTER the last use of p, giving ~1 full
// step of load->use distance without any register copies (unroll-by-2 buffers).
template<int STORE_ALL>
__device__ __forceinline__ void scan_step(float m[24], float p[9],
    const float* __restrict__ P, int t, int lane, float* __restrict__ Rout)
{
  float s[8], pe[8];
  #pragma unroll
  for (int n=0;n<8;++n)
    s[n] = fmaf(m[n*3+2], p[2], fmaf(m[n*3+1], p[1], m[n*3]*p[0]));
  #pragma unroll
  for (int n=0;n<8;++n) pe[n] = fast_exp2(s[n]);
  float S = ((pe[0]+pe[1])+(pe[2]+pe[3])) + ((pe[4]+pe[5])+(pe[6]+pe[7]));
  float rinv = fast_rcp(S);
  if (STORE_ALL || t == T_-1){
    #pragma unroll
    for (int d=0; d<3; ++d){
      float rd = pe[0]*m[d];
      #pragma unroll
      for (int n=1;n<8;++n) rd = fmaf(pe[n], m[n*3+d], rd);
      rd *= rinv;
      if (STORE_ALL) Rout[(t*3+d)*64 + lane] = rd;
      else           Rout[d*64 + lane] = rd;
    }
  }
  float w[8];
  #pragma unroll
  for (int n=0;n<8;++n) w[n] = pe[n]*rinv;
  float v0=p[3],v1=p[4],v2=p[5], e0=p[6],e1=p[7],e2=p[8];
  #pragma unroll
  for (int n=0;n<8;++n){
    m[n*3]   = fmaf(w[n], fmaf(-e0, m[n*3],   v0), m[n*3]);
    m[n*3+1] = fmaf(w[n], fmaf(-e1, m[n*3+1], v1), m[n*3+1]);
    m[n*3+2] = fmaf(w[n], fmaf(-e2, m[n*3+2], v2), m[n*3+2]);
  }
  // prefetch p for step t+2 (last use of p was the update above)
  int tn = t + 2; if (tn > T_-1) tn = T_-1;
  const float* Pn = P + (long)tn*576;
  #pragma unroll
  for (int j=0;j<9;++j) p[j] = Pn[j*64+lane];
}

template<int STORE_ALL>
__device__ __forceinline__ void scan_core(const float* __restrict__ P,
                                          float* __restrict__ Rout, int lane)
{
  float m[24];
  #pragma unroll
  for (int i=0;i<24;++i) m[i]=0.f;
  float pa[9], pb[9];
  #pragma unroll
  for (int j=0;j<9;++j){ pa[j] = P[j*64+lane]; pb[j] = P[576 + j*64+lane]; }
  #pragma unroll 1
  for (int t=0;t<T_;t+=2){
    scan_step<STORE_ALL>(m, pa, P, t,   lane, Rout);
    scan_step<STORE_ALL>(m, pb, P, t+1, lane, Rout);
  }
}

__global__ __launch_bounds__(64) void k_scan1(const float* __restrict__ P1,
                                              float* __restrict__ R1)
{
  scan_core<1>(P1, R1, (int)threadIdx.x);
}

// ---------------- Kernel 3: fused z1=x@W1o, o1=sigmoid(z1+b+read*Wr), P2=o1@W2kwg -------
__global__ __launch_bounds__(256) void k_fused(const float* __restrict__ X,
    const float* __restrict__ W1o, const float* __restrict__ b1o,
    const float* __restrict__ R1,
    const float* __restrict__ W2k, const float* __restrict__ b2k,
    const float* __restrict__ W2w, const float* __restrict__ b2w,
    const float* __restrict__ W2g, const float* __restrict__ b2g,
    float* __restrict__ P2, float* __restrict__ O1last)
{
  __shared__ __align__(16) float At[128*20];   // transposed A tile [k][row], pad 16->20
  __shared__ __align__(16) float o1t[16*516];  // o1 tile [row][col], pad 512->516
  __shared__ float wrS[3*512];
  __shared__ float b1S[512];
  __shared__ float rdS[48];
  int tid = threadIdx.x;
  long r0 = (long)blockIdx.x * 16;
  int b = (int)(r0 >> 9); int t0 = (int)(r0 & 511);
  const float4* X4 = (const float4*)(X + r0*128);
  #pragma unroll
  for (int it=0; it<2; ++it){
    int f4 = tid + it*256;
    float4 v = X4[f4];
    int f = f4*4; int row = f>>7; int k = f&127;
    At[(k  )*20+row] = v.x;
    At[(k+1)*20+row] = v.y;
    At[(k+2)*20+row] = v.z;
    At[(k+3)*20+row] = v.w;
  }
  #pragma unroll
  for (int it=0; it<6; ++it){
    int f = tid + it*256; // 1536 read-part weights W1o[128..130][:]
    wrS[f] = W1o[(128 + (f>>9))*512 + (f&511)];
  }
  b1S[tid] = b1o[tid]; b1S[tid+256] = b1o[tid+256];
  if (tid < 48){
    int i = tid/3, d = tid%3;
    rdS[tid] = R1[((t0+i)*3+d)*64 + b];
  }
  __syncthreads();
  int c0 = tid, c1 = tid+256;
  float acc0[16], acc1[16];
  #pragma unroll
  for (int r=0;r<16;++r){acc0[r]=0.f;acc1[r]=0.f;}
  #pragma unroll 4
  for (int k=0;k<128;++k){
    float w0 = W1o[k*512 + c0];
    float w1 = W1o[k*512 + c1];
    const float4* a4 = (const float4*)(At + k*20);
    float av[16]; float4 q;
    q = a4[0]; av[0]=q.x; av[1]=q.y; av[2]=q.z; av[3]=q.w;
    q = a4[1]; av[4]=q.x; av[5]=q.y; av[6]=q.z; av[7]=q.w;
    q = a4[2]; av[8]=q.x; av[9]=q.y; av[10]=q.z; av[11]=q.w;
    q = a4[3]; av[12]=q.x; av[13]=q.y; av[14]=q.z; av[15]=q.w;
    #pragma unroll
    for (int r=0;r<16;++r){
      acc0[r] = fmaf(av[r], w0, acc0[r]);
      acc1[r] = fmaf(av[r], w1, acc1[r]);
    }
  }
  #pragma unroll
  for (int r=0;r<16;++r){
    float add0 = b1S[c0] + rdS[r*3]*wrS[c0] + rdS[r*3+1]*wrS[512+c0] + rdS[r*3+2]*wrS[1024+c0];
    float add1 = b1S[c1] + rdS[r*3]*wrS[c1] + rdS[r*3+1]*wrS[512+c1] + rdS[r*3+2]*wrS[1024+c1];
    o1t[r*516+c0] = sigmoidf_(acc0[r]+add0);
    o1t[r*516+c1] = sigmoidf_(acc1[r]+add1);
  }
  __syncthreads();
  if (tid < 144){
    int r = tid/9, j = tid%9;
    const float* W2x; float bias; int jj;
    if (j<3){ W2x=W2k; jj=j;   bias=b2k[jj]; }
    else if (j<6){ W2x=W2w; jj=j-3; bias=b2w[jj]; }
    else { W2x=W2g; jj=j-6; bias=b2g[jj]; }
    float acc = bias;
    #pragma unroll 8
    for (int c=0;c<512;++c) acc = fmaf(o1t[r*516+c], W2x[c*3+jj], acc);
    if (j<3) acc *= LOG2E;
    else if (j<6) acc *= 0.1f;
    else acc = 0.1f*sigmoidf_(acc);
    P2[((long)(t0+r)*9+j)*64 + b] = acc;
  }
  if (t0 == 496){
    O1last[b*512 + tid]       = o1t[15*516 + tid];
    O1last[b*512 + tid + 256] = o1t[15*516 + tid + 256];
  }
}

// ---------------- Kernel 4: block0 = scan2 (final read only); blocks 1..64 = Opart ------
__global__ __launch_bounds__(128) void k_scan2_opart(const float* __restrict__ P2,
    float* __restrict__ R2F,
    const float* __restrict__ O1last, const float* __restrict__ W2o,
    const float* __restrict__ b2o, float* __restrict__ Opart)
{
  if (blockIdx.x == 0){
    if (threadIdx.x < 64) scan_core<0>(P2, R2F, (int)threadIdx.x);
    return;
  }
  __shared__ __align__(16) float s[512];
  int b = blockIdx.x - 1; int tid = threadIdx.x;
  float4 v = ((const float4*)(O1last + b*512))[tid];
  ((float4*)s)[tid] = v;
  __syncthreads();
  float acc = b2o[tid];
  #pragma unroll 8
  for (int n=0;n<512;++n) acc = fmaf(s[n], W2o[n*128+tid], acc);
  Opart[b*128+tid] = acc;
}

// ---------------- Kernel 5: out = sigmoid(Opart + read2 @ W2o[512:515]) -----------------
__global__ __launch_bounds__(256) void k_final(const float* __restrict__ Opart,
    const float* __restrict__ R2F, const float* __restrict__ W2o,
    float* __restrict__ out)
{
  int idx = blockIdx.x*256 + threadIdx.x;
  if (idx < 8192){
    int b = idx >> 7; int o = idx & 127;
    float r0 = R2F[b], r1 = R2F[64+b], r2 = R2F[128+b];
    float v = Opart[idx]
            + r0*W2o[512*128+o] + r1*W2o[513*128+o] + r2*W2o[514*128+o];
    out[idx] = sigmoidf_(v);
  }
}

extern "C" void kernel_launch(void* const* d_in, const int* in_sizes, int n_in,
                              void* d_out, int out_size, void* d_ws, size_t ws_size,
                              hipStream_t stream)
{
  const float* X  = (const float*)d_in[0];
  const float* W1k= (const float*)d_in[1]; const float* b1k=(const float*)d_in[2];
  const float* W1w= (const float*)d_in[3]; const float* b1w=(const float*)d_in[4];
  const float* W1g= (const float*)d_in[5]; const float* b1g=(const float*)d_in[6];
  const float* W1o= (const float*)d_in[7]; const float* b1o=(const float*)d_in[8];
  const float* W2k= (const float*)d_in[9]; const float* b2k=(const float*)d_in[10];
  const float* W2w= (const float*)d_in[11]; const float* b2w=(const float*)d_in[12];
  const float* W2g= (const float*)d_in[13]; const float* b2g=(const float*)d_in[14];
  const float* W2o= (const float*)d_in[15]; const float* b2o=(const float*)d_in[16];

  float* ws = (float*)d_ws;
  float* P1     = ws;               // 512*9*64   = 294912
  float* R1     = P1 + 294912;      // 512*3*64   =  98304
  float* P2     = R1 + 98304;       // 512*9*64   = 294912
  float* O1last = P2 + 294912;      // 64*512     =  32768
  float* R2F    = O1last + 32768;   // 3*64       =    192
  float* Opart  = R2F + 192;        // 64*128     =   8192
  float* out    = (float*)d_out;

  hipLaunchKernelGGL(k_proj1, dim3(512), dim3(256), 0, stream,
                     X, W1k,b1k, W1w,b1w, W1g,b1g, P1);
  hipLaunchKernelGGL(k_scan1, dim3(1), dim3(64), 0, stream, P1, R1);
  hipLaunchKernelGGL(k_fused, dim3(2048), dim3(256), 0, stream,
                     X, W1o, b1o, R1, W2k,b2k, W2w,b2w, W2g,b2g, P2, O1last);
  hipLaunchKernelGGL(k_scan2_opart, dim3(65), dim3(128), 0, stream,
                     P2, R2F, O1last, W2o, b2o, Opart);
  hipLaunchKernelGGL(k_final, dim3(32), dim3(256), 0, stream,
                     Opart, R2F, W2o, out);
}

// Round 3
// 425.418 us; speedup vs baseline: 1.5540x; 1.4344x over previous
//
#include <hip/hip_runtime.h>
#include <hip/hip_bf16.h>

#define B_ 64
#define T_ 512
#define LOG2E 1.4426950408889634f

typedef __attribute__((ext_vector_type(8))) short short8;
typedef __attribute__((ext_vector_type(4))) float f32x4;

__device__ __forceinline__ float fast_exp2(float x){ return __builtin_amdgcn_exp2f(x); }
__device__ __forceinline__ float fast_rcp(float x){ return __builtin_amdgcn_rcpf(x); }
__device__ __forceinline__ float sigmoidf_(float x){ return fast_rcp(1.0f + fast_exp2(-x*LOG2E)); }
__device__ __forceinline__ unsigned short f2bf(float f){
  union{float f; unsigned u;} v; v.f = f;
  unsigned r = v.u + 0x7fffu + ((v.u>>16)&1u);
  return (unsigned short)(r>>16);
}

// ---------------- Kernel 0: prep bf16 weights -------------------------------------------
// W1oTb[n*128+k] = bf16(W1o[k*512+n])  (512x128, k-major per output col)
// W2cTb[j*512+c] = bf16(W2{k,w,g}[c*3+jj]) for j<9 else 0   (16x512, c(k)-major)
__global__ __launch_bounds__(256) void k_prep(const float* __restrict__ W1o,
    const float* __restrict__ W2k, const float* __restrict__ W2w, const float* __restrict__ W2g,
    unsigned short* __restrict__ W1oTb, unsigned short* __restrict__ W2cTb)
{
  int idx = blockIdx.x*256 + threadIdx.x;
  if (idx < 65536){
    int n = idx >> 7, k = idx & 127;
    W1oTb[idx] = f2bf(W1o[k*512 + n]);
  }
  if (idx < 8192){
    int j = idx >> 9, c = idx & 511;
    float v = 0.f;
    if (j < 3) v = W2k[c*3 + j];
    else if (j < 6) v = W2w[c*3 + j - 3];
    else if (j < 9) v = W2g[c*3 + j - 6];
    W2cTb[idx] = f2bf(v);
  }
}

// ---------------- Kernel 1: P1[t][j][b] = proj of x (k*log2e, 0.1*v, 0.1*sigmoid(g)) ----
__global__ __launch_bounds__(256) void k_proj1(const float* __restrict__ X,
    const float* __restrict__ Wk, const float* __restrict__ bk,
    const float* __restrict__ Ww, const float* __restrict__ bw,
    const float* __restrict__ Wg, const float* __restrict__ bg,
    float* __restrict__ P1)
{
  __shared__ __align__(16) float A[64*132];
  __shared__ float Wc[128*12];
  __shared__ float bb[9];
  int tid = threadIdx.x;
  long r0 = (long)blockIdx.x * 64;
  const float4* X4 = (const float4*)(X + r0*128);
  #pragma unroll
  for (int it=0; it<8; ++it){
    int f4 = tid + it*256;
    float4 v = X4[f4];
    int f = f4*4; int row = f>>7; int k = f&127;
    A[row*132+k]   = v.x; A[row*132+k+1] = v.y;
    A[row*132+k+2] = v.z; A[row*132+k+3] = v.w;
  }
  #pragma unroll
  for (int it=0; it<5; ++it){
    int w = tid + it*256;
    if (w < 1152){
      int k = w/9, j = w%9;
      float val;
      if (j<3) val = Wk[k*3+j]; else if (j<6) val = Ww[k*3+j-3]; else val = Wg[k*3+j-6];
      Wc[k*12+j] = val;
    }
  }
  if (tid < 9){
    float v; if (tid<3) v = bk[tid]; else if (tid<6) v = bw[tid-3]; else v = bg[tid-6];
    bb[tid] = v;
  }
  __syncthreads();
  for (int o = tid; o < 576; o += 256){
    int row = o/9, j = o%9;
    float acc = bb[j];
    #pragma unroll 8
    for (int k=0;k<128;++k) acc = fmaf(A[row*132+k], Wc[k*12+j], acc);
    if (j<3) acc *= LOG2E;
    else if (j<6) acc *= 0.1f;
    else acc = 0.1f * sigmoidf_(acc);
    long r = r0 + row;
    int b = (int)(r >> 9); int t = (int)(r & 511);
    P1[(t*9+j)*64 + b] = acc;
  }
}

// ---------------- scan: one lane = one batch, 8-deep register prefetch pipeline ---------
template<int STORE_ALL>
__device__ __forceinline__ void scan_body(float m[24], const float p[9],
                                          int t, int lane, float* __restrict__ Rout)
{
  float s_[8], pe[8];
  #pragma unroll
  for (int n=0;n<8;++n)
    s_[n] = fmaf(m[n*3+2], p[2], fmaf(m[n*3+1], p[1], m[n*3]*p[0]));
  #pragma unroll
  for (int n=0;n<8;++n) pe[n] = fast_exp2(s_[n]);
  float S = ((pe[0]+pe[1])+(pe[2]+pe[3])) + ((pe[4]+pe[5])+(pe[6]+pe[7]));
  float rinv = fast_rcp(S);
  if (STORE_ALL || t == T_-1){
    #pragma unroll
    for (int d=0; d<3; ++d){
      float rd = pe[0]*m[d];
      #pragma unroll
      for (int n=1;n<8;++n) rd = fmaf(pe[n], m[n*3+d], rd);
      rd *= rinv;
      if (STORE_ALL) Rout[(t*3+d)*64 + lane] = rd;
      else           Rout[d*64 + lane] = rd;
    }
  }
  float w[8];
  #pragma unroll
  for (int n=0;n<8;++n) w[n] = pe[n]*rinv;
  float v0=p[3],v1=p[4],v2=p[5], e0=p[6],e1=p[7],e2=p[8];
  #pragma unroll
  for (int n=0;n<8;++n){
    m[n*3]   = fmaf(w[n], fmaf(-e0, m[n*3],   v0), m[n*3]);
    m[n*3+1] = fmaf(w[n], fmaf(-e1, m[n*3+1], v1), m[n*3+1]);
    m[n*3+2] = fmaf(w[n], fmaf(-e2, m[n*3+2], v2), m[n*3+2]);
  }
}

template<int STORE_ALL>
__device__ __forceinline__ void scan_core(const float* __restrict__ P,
                                          float* __restrict__ Rout, int lane)
{
  float m[24];
  #pragma unroll
  for (int i=0;i<24;++i) m[i]=0.f;
  float pp[8][9];
  #pragma unroll
  for (int d=0; d<8; ++d)
    #pragma unroll
    for (int j=0;j<9;++j) pp[d][j] = P[(long)d*576 + j*64 + lane];
  #pragma unroll 1
  for (int t=0; t<T_; t+=8){
    #pragma unroll
    for (int d=0; d<8; ++d){
      scan_body<STORE_ALL>(m, pp[d], t+d, lane, Rout);
      int tn = t + d + 8; if (tn > T_-1) tn = T_-1;
      const float* Pn = P + (long)tn*576;
      #pragma unroll
      for (int j=0;j<9;++j) pp[d][j] = Pn[j*64 + lane];
    }
  }
}

__global__ __launch_bounds__(64) void k_scan1(const float* __restrict__ P1,
                                              float* __restrict__ R1)
{
  scan_core<1>(P1, R1, (int)threadIdx.x);
}

// ---------------- Kernel 3: MFMA fused z1=x@W1o, o1=sigmoid(.), P2=o1@W2c ---------------
// Block = 16 rows (one b, t0..t0+15) x 512 cols. 4 waves, wave w owns cols [128w,128w+128).
__global__ __launch_bounds__(256) void k_fused(const float* __restrict__ X,
    const float* __restrict__ W1o, const float* __restrict__ b1o,
    const float* __restrict__ R1,
    const unsigned short* __restrict__ W1oTb, const unsigned short* __restrict__ W2cTb,
    const float* __restrict__ b2k, const float* __restrict__ b2w, const float* __restrict__ b2g,
    float* __restrict__ P2, float* __restrict__ O1last)
{
  __shared__ __align__(16) float rdS[48];
  __shared__ __align__(16) unsigned short o1b[16*520];  // bf16 o1 tile, row stride 520
  __shared__ __align__(16) float pSum[4*16*16];
  int tid = threadIdx.x;
  int w = tid >> 6, lane = tid & 63;
  int n16 = lane & 15, g4 = lane >> 4;
  long r0 = (long)blockIdx.x * 16;
  int b = (int)(r0 >> 9); int t0 = (int)(r0 & 511);

  if (tid < 48){
    int i = tid/3, d = tid%3;
    rdS[tid] = R1[((t0+i)*3+d)*64 + b];
  }

  // A fragments: lane holds X[r0+n16][q*32 + g4*8 .. +8] as bf16
  short8 afr[4];
  const float* Xrow = X + (r0 + n16)*128;
  #pragma unroll
  for (int q=0;q<4;++q){
    f32x4 x0 = *(const f32x4*)(Xrow + q*32 + g4*8);
    f32x4 x1 = *(const f32x4*)(Xrow + q*32 + g4*8 + 4);
    short8 a;
    a[0]=(short)f2bf(x0[0]); a[1]=(short)f2bf(x0[1]);
    a[2]=(short)f2bf(x0[2]); a[3]=(short)f2bf(x0[3]);
    a[4]=(short)f2bf(x1[0]); a[5]=(short)f2bf(x1[1]);
    a[6]=(short)f2bf(x1[2]); a[7]=(short)f2bf(x1[3]);
    afr[q]=a;
  }
  __syncthreads();  // rdS ready

  // read-correction coefficients for this lane's 4 rows (rowloc = g4*4+reg)
  f32x4 ra = *(const f32x4*)(rdS + g4*12);
  f32x4 rb = *(const f32x4*)(rdS + g4*12 + 4);
  f32x4 rc = *(const f32x4*)(rdS + g4*12 + 8);
  float rd0[4] = { ra[0], ra[3], rb[2], rc[1] };
  float rd1[4] = { ra[1], rb[0], rb[3], rc[2] };
  float rd2[4] = { ra[2], rb[1], rc[0], rc[3] };

  #pragma unroll
  for (int tt=0; tt<8; ++tt){
    int gc = w*128 + tt*16 + n16;
    f32x4 acc = {0.f,0.f,0.f,0.f};
    #pragma unroll
    for (int q=0;q<4;++q){
      short8 bf = *(const short8*)(W1oTb + gc*128 + q*32 + g4*8);
      acc = __builtin_amdgcn_mfma_f32_16x16x32_bf16(afr[q], bf, acc, 0,0,0);
    }
    float bias = b1o[gc];
    float wr0 = W1o[128*512+gc], wr1 = W1o[129*512+gc], wr2 = W1o[130*512+gc];
    #pragma unroll
    for (int reg=0; reg<4; ++reg){
      int rowloc = g4*4 + reg;
      float z = acc[reg] + bias + rd0[reg]*wr0 + rd1[reg]*wr1 + rd2[reg]*wr2;
      float o1 = sigmoidf_(z);
      o1b[rowloc*520 + gc] = f2bf(o1);
      if (t0 == 496 && rowloc == 15) O1last[b*512 + gc] = o1;
    }
  }

  // tail MFMA: partial P2 over this wave's 128 cols (reads only own writes; no barrier)
  f32x4 accP = {0.f,0.f,0.f,0.f};
  #pragma unroll
  for (int q2=0; q2<4; ++q2){
    int kk = w*128 + q2*32;
    short8 a2 = *(const short8*)(o1b + n16*520 + kk + g4*8);
    short8 bb2 = *(const short8*)(W2cTb + n16*512 + kk + g4*8);
    accP = __builtin_amdgcn_mfma_f32_16x16x32_bf16(a2, bb2, accP, 0,0,0);
  }
  #pragma unroll
  for (int reg=0;reg<4;++reg){
    int rowloc = g4*4+reg;
    pSum[w*256 + rowloc*16 + n16] = accP[reg];
  }
  __syncthreads();
  if (tid < 144){
    int r = tid/9, j = tid%9;
    float s = pSum[r*16+j] + pSum[256+r*16+j] + pSum[512+r*16+j] + pSum[768+r*16+j];
    float outv;
    if (j<3){ s += b2k[j]; outv = s*LOG2E; }
    else if (j<6){ s += b2w[j-3]; outv = 0.1f*s; }
    else { s += b2g[j-6]; outv = 0.1f*sigmoidf_(s); }
    P2[((long)(t0+r)*9+j)*64 + b] = outv;
  }
}

// ---------------- Kernel 4: block0 = scan2 (final read only); blocks 1..64 = Opart ------
__global__ __launch_bounds__(128) void k_scan2_opart(const float* __restrict__ P2,
    float* __restrict__ R2F,
    const float* __restrict__ O1last, const float* __restrict__ W2o,
    const float* __restrict__ b2o, float* __restrict__ Opart)
{
  if (blockIdx.x == 0){
    if (threadIdx.x < 64) scan_core<0>(P2, R2F, (int)threadIdx.x);
    return;
  }
  __shared__ __align__(16) float s[512];
  int b = blockIdx.x - 1; int tid = threadIdx.x;
  float4 v = ((const float4*)(O1last + b*512))[tid];
  ((float4*)s)[tid] = v;
  __syncthreads();
  float acc = b2o[tid];
  #pragma unroll 8
  for (int n=0;n<512;++n) acc = fmaf(s[n], W2o[n*128+tid], acc);
  Opart[b*128+tid] = acc;
}

// ---------------- Kernel 5: out = sigmoid(Opart + read2 @ W2o[512:515]) -----------------
__global__ __launch_bounds__(256) void k_final(const float* __restrict__ Opart,
    const float* __restrict__ R2F, const float* __restrict__ W2o,
    float* __restrict__ out)
{
  int idx = blockIdx.x*256 + threadIdx.x;
  if (idx < 8192){
    int b = idx >> 7; int o = idx & 127;
    float r0 = R2F[b], r1 = R2F[64+b], r2 = R2F[128+b];
    float v = Opart[idx]
            + r0*W2o[512*128+o] + r1*W2o[513*128+o] + r2*W2o[514*128+o];
    out[idx] = sigmoidf_(v);
  }
}

extern "C" void kernel_launch(void* const* d_in, const int* in_sizes, int n_in,
                              void* d_out, int out_size, void* d_ws, size_t ws_size,
                              hipStream_t stream)
{
  const float* X  = (const float*)d_in[0];
  const float* W1k= (const float*)d_in[1]; const float* b1k=(const float*)d_in[2];
  const float* W1w= (const float*)d_in[3]; const float* b1w=(const float*)d_in[4];
  const float* W1g= (const float*)d_in[5]; const float* b1g=(const float*)d_in[6];
  const float* W1o= (const float*)d_in[7]; const float* b1o=(const float*)d_in[8];
  const float* W2k= (const float*)d_in[9]; const float* b2k=(const float*)d_in[10];
  const float* W2w= (const float*)d_in[11]; const float* b2w=(const float*)d_in[12];
  const float* W2g= (const float*)d_in[13]; const float* b2g=(const float*)d_in[14];
  const float* W2o= (const float*)d_in[15]; const float* b2o=(const float*)d_in[16];

  float* ws = (float*)d_ws;
  float* P1     = ws;               // 512*9*64   = 294912
  float* R1     = P1 + 294912;      // 512*3*64   =  98304
  float* P2     = R1 + 98304;       // 512*9*64   = 294912
  float* O1last = P2 + 294912;      // 64*512     =  32768
  float* R2F    = O1last + 32768;   // 3*64       =    192
  float* Opart  = R2F + 192;        // 64*128     =   8192
  unsigned short* W1oTb = (unsigned short*)(Opart + 8192);  // 512*128 bf16
  unsigned short* W2cTb = W1oTb + 65536;                    // 16*512 bf16
  float* out    = (float*)d_out;

  hipLaunchKernelGGL(k_prep, dim3(256), dim3(256), 0, stream,
                     W1o, W2k, W2w, W2g, W1oTb, W2cTb);
  hipLaunchKernelGGL(k_proj1, dim3(512), dim3(256), 0, stream,
                     X, W1k,b1k, W1w,b1w, W1g,b1g, P1);
  hipLaunchKernelGGL(k_scan1, dim3(1), dim3(64), 0, stream, P1, R1);
  hipLaunchKernelGGL(k_fused, dim3(2048), dim3(256), 0, stream,
                     X, W1o, b1o, R1, W1oTb, W2cTb, b2k, b2w, b2g, P2, O1last);
  hipLaunchKernelGGL(k_scan2_opart, dim3(65), dim3(128), 0, stream,
                     P2, R2F, O1last, W2o, b2o, Opart);
  hipLaunchKernelGGL(k_final, dim3(32), dim3(256), 0, stream,
                     Opart, R2F, W2o, out);
}

// Round 4
// 366.869 us; speedup vs baseline: 1.8020x; 1.1596x over previous
//
#include <hip/hip_runtime.h>
#include <hip/hip_bf16.h>

#define B_ 64
#define T_ 512
#define LOG2E 1.4426950408889634f
#define PHASE_STEPS 8
#define NPHASE (T_/PHASE_STEPS)

typedef __attribute__((ext_vector_type(8))) short short8;
typedef __attribute__((ext_vector_type(4))) float f32x4;

__device__ __forceinline__ float fast_exp2(float x){ return __builtin_amdgcn_exp2f(x); }
__device__ __forceinline__ float fast_rcp(float x){ return __builtin_amdgcn_rcpf(x); }
__device__ __forceinline__ float sigmoidf_(float x){ return fast_rcp(1.0f + fast_exp2(-x*LOG2E)); }
__device__ __forceinline__ unsigned short f2bf(float f){
  union{float f; unsigned u;} v; v.f = f;
  unsigned r = v.u + 0x7fffu + ((v.u>>16)&1u);
  return (unsigned short)(r>>16);
}

// ---------------- Kernel 0: prep bf16 weights -------------------------------------------
__global__ __launch_bounds__(256) void k_prep(const float* __restrict__ W1o,
    const float* __restrict__ W2k, const float* __restrict__ W2w, const float* __restrict__ W2g,
    unsigned short* __restrict__ W1oTb, unsigned short* __restrict__ W2cTb)
{
  int idx = blockIdx.x*256 + threadIdx.x;
  if (idx < 65536){
    int n = idx >> 7, k = idx & 127;
    W1oTb[idx] = f2bf(W1o[k*512 + n]);
  }
  if (idx < 8192){
    int j = idx >> 9, c = idx & 511;
    float v = 0.f;
    if (j < 3) v = W2k[c*3 + j];
    else if (j < 6) v = W2w[c*3 + j - 3];
    else if (j < 9) v = W2g[c*3 + j - 6];
    W2cTb[idx] = f2bf(v);
  }
}

// ---------------- Kernel 1: P1[t][j][b] = proj of x (k*log2e, 0.1*v, 0.1*sigmoid(g)) ----
__global__ __launch_bounds__(256) void k_proj1(const float* __restrict__ X,
    const float* __restrict__ Wk, const float* __restrict__ bk,
    const float* __restrict__ Ww, const float* __restrict__ bw,
    const float* __restrict__ Wg, const float* __restrict__ bg,
    float* __restrict__ P1)
{
  __shared__ __align__(16) float A[64*132];
  __shared__ float Wc[128*12];
  __shared__ float bb[9];
  int tid = threadIdx.x;
  long r0 = (long)blockIdx.x * 64;
  const float4* X4 = (const float4*)(X + r0*128);
  #pragma unroll
  for (int it=0; it<8; ++it){
    int f4 = tid + it*256;
    float4 v = X4[f4];
    int f = f4*4; int row = f>>7; int k = f&127;
    A[row*132+k]   = v.x; A[row*132+k+1] = v.y;
    A[row*132+k+2] = v.z; A[row*132+k+3] = v.w;
  }
  #pragma unroll
  for (int it=0; it<5; ++it){
    int w = tid + it*256;
    if (w < 1152){
      int k = w/9, j = w%9;
      float val;
      if (j<3) val = Wk[k*3+j]; else if (j<6) val = Ww[k*3+j-3]; else val = Wg[k*3+j-6];
      Wc[k*12+j] = val;
    }
  }
  if (tid < 9){
    float v; if (tid<3) v = bk[tid]; else if (tid<6) v = bw[tid-3]; else v = bg[tid-6];
    bb[tid] = v;
  }
  __syncthreads();
  for (int o = tid; o < 576; o += 256){
    int row = o/9, j = o%9;
    float acc = bb[j];
    #pragma unroll 8
    for (int k=0;k<128;++k) acc = fmaf(A[row*132+k], Wc[k*12+j], acc);
    if (j<3) acc *= LOG2E;
    else if (j<6) acc *= 0.1f;
    else acc = 0.1f * sigmoidf_(acc);
    long r = r0 + row;
    int b = (int)(r >> 9); int t = (int)(r & 511);
    P1[(t*9+j)*64 + b] = acc;
  }
}

// ---------------- scan step body (registers in, registers out) --------------------------
template<int STORE_ALL>
__device__ __forceinline__ void scan_body(float m[24], const float p[9],
                                          int t, int lane, float* __restrict__ Rout)
{
  float s_[8], pe[8];
  #pragma unroll
  for (int n=0;n<8;++n)
    s_[n] = fmaf(m[n*3+2], p[2], fmaf(m[n*3+1], p[1], m[n*3]*p[0]));
  #pragma unroll
  for (int n=0;n<8;++n) pe[n] = fast_exp2(s_[n]);
  float S = ((pe[0]+pe[1])+(pe[2]+pe[3])) + ((pe[4]+pe[5])+(pe[6]+pe[7]));
  float rinv = fast_rcp(S);
  if (STORE_ALL || t == T_-1){
    #pragma unroll
    for (int d=0; d<3; ++d){
      float rd = pe[0]*m[d];
      #pragma unroll
      for (int n=1;n<8;++n) rd = fmaf(pe[n], m[n*3+d], rd);
      rd *= rinv;
      if (STORE_ALL) Rout[(t*3+d)*64 + lane] = rd;
      else           Rout[d*64 + lane] = rd;
    }
  }
  float w[8];
  #pragma unroll
  for (int n=0;n<8;++n) w[n] = pe[n]*rinv;
  float v0=p[3],v1=p[4],v2=p[5], e0=p[6],e1=p[7],e2=p[8];
  #pragma unroll
  for (int n=0;n<8;++n){
    m[n*3]   = fmaf(w[n], fmaf(-e0, m[n*3],   v0), m[n*3]);
    m[n*3+1] = fmaf(w[n], fmaf(-e1, m[n*3+1], v1), m[n*3+1]);
    m[n*3+2] = fmaf(w[n], fmaf(-e2, m[n*3+2], v2), m[n*3+2]);
  }
}

// ---------------- pipelined scan: wave0 = scan from LDS, wave1 = DMA global->LDS --------
// P is [T][9][64] contiguous; a phase = 8 steps = 4608 floats, double-buffered in LDS.
// One __syncthreads per phase; the barrier's vmcnt(0) drain lands on the DMA wave and is
// hidden behind the scan wave's ~8 steps of compute.
template<int STORE_ALL>
__device__ __forceinline__ void scan_pipelined(const float* __restrict__ P,
                                               float* __restrict__ Rout)
{
  __shared__ __align__(16) float buf[2][PHASE_STEPS*576];
  int tid = threadIdx.x;
  int wv = tid >> 6, lane = tid & 63;
  if (wv == 1){
    #pragma unroll 1
    for (int p = 0; p < NPHASE; ++p){
      const float4* src = (const float4*)(P + (long)p*PHASE_STEPS*576);
      float4* dst = (float4*)buf[p&1];
      float4 tmp[18];
      #pragma unroll
      for (int i=0;i<18;++i) tmp[i] = src[lane + i*64];
      #pragma unroll
      for (int i=0;i<18;++i) dst[lane + i*64] = tmp[i];
      __syncthreads();
    }
  } else {
    float m[24];
    #pragma unroll
    for (int i=0;i<24;++i) m[i]=0.f;
    __syncthreads();  // buf0 ready
    #pragma unroll 1
    for (int p = 0; p < NPHASE; ++p){
      const float* bp = buf[p&1];
      float pv[9];
      #pragma unroll
      for (int j=0;j<9;++j) pv[j] = bp[j*64 + lane];
      #pragma unroll
      for (int s=0;s<PHASE_STEPS;++s){
        float pn[9];
        if (s < PHASE_STEPS-1){
          #pragma unroll
          for (int j=0;j<9;++j) pn[j] = bp[(s+1)*576 + j*64 + lane];
        }
        scan_body<STORE_ALL>(m, pv, p*PHASE_STEPS+s, lane, Rout);
        if (s < PHASE_STEPS-1){
          #pragma unroll
          for (int j=0;j<9;++j) pv[j] = pn[j];
        }
      }
      if (p < NPHASE-1) __syncthreads();
    }
  }
}

__global__ __launch_bounds__(128) void k_scan1(const float* __restrict__ P1,
                                               float* __restrict__ R1)
{
  scan_pipelined<1>(P1, R1);
}

// ---------------- Kernel 3: MFMA fused z1=x@W1o, o1=sigmoid(.), P2=o1@W2c ---------------
__global__ __launch_bounds__(256) void k_fused(const float* __restrict__ X,
    const float* __restrict__ W1o, const float* __restrict__ b1o,
    const float* __restrict__ R1,
    const unsigned short* __restrict__ W1oTb, const unsigned short* __restrict__ W2cTb,
    const float* __restrict__ b2k, const float* __restrict__ b2w, const float* __restrict__ b2g,
    float* __restrict__ P2, float* __restrict__ O1last)
{
  __shared__ __align__(16) float rdS[48];
  __shared__ __align__(16) unsigned short o1b[16*520];
  __shared__ __align__(16) float pSum[4*16*16];
  int tid = threadIdx.x;
  int w = tid >> 6, lane = tid & 63;
  int n16 = lane & 15, g4 = lane >> 4;
  long r0 = (long)blockIdx.x * 16;
  int b = (int)(r0 >> 9); int t0 = (int)(r0 & 511);

  if (tid < 48){
    int i = tid/3, d = tid%3;
    rdS[tid] = R1[((t0+i)*3+d)*64 + b];
  }

  short8 afr[4];
  const float* Xrow = X + (r0 + n16)*128;
  #pragma unroll
  for (int q=0;q<4;++q){
    f32x4 x0 = *(const f32x4*)(Xrow + q*32 + g4*8);
    f32x4 x1 = *(const f32x4*)(Xrow + q*32 + g4*8 + 4);
    short8 a;
    a[0]=(short)f2bf(x0[0]); a[1]=(short)f2bf(x0[1]);
    a[2]=(short)f2bf(x0[2]); a[3]=(short)f2bf(x0[3]);
    a[4]=(short)f2bf(x1[0]); a[5]=(short)f2bf(x1[1]);
    a[6]=(short)f2bf(x1[2]); a[7]=(short)f2bf(x1[3]);
    afr[q]=a;
  }
  __syncthreads();

  f32x4 ra = *(const f32x4*)(rdS + g4*12);
  f32x4 rb = *(const f32x4*)(rdS + g4*12 + 4);
  f32x4 rc = *(const f32x4*)(rdS + g4*12 + 8);
  float rd0[4] = { ra[0], ra[3], rb[2], rc[1] };
  float rd1[4] = { ra[1], rb[0], rb[3], rc[2] };
  float rd2[4] = { ra[2], rb[1], rc[0], rc[3] };

  #pragma unroll
  for (int tt=0; tt<8; ++tt){
    int gc = w*128 + tt*16 + n16;
    f32x4 acc = {0.f,0.f,0.f,0.f};
    #pragma unroll
    for (int q=0;q<4;++q){
      short8 bf = *(const short8*)(W1oTb + gc*128 + q*32 + g4*8);
      acc = __builtin_amdgcn_mfma_f32_16x16x32_bf16(afr[q], bf, acc, 0,0,0);
    }
    float bias = b1o[gc];
    float wr0 = W1o[128*512+gc], wr1 = W1o[129*512+gc], wr2 = W1o[130*512+gc];
    #pragma unroll
    for (int reg=0; reg<4; ++reg){
      int rowloc = g4*4 + reg;
      float z = acc[reg] + bias + rd0[reg]*wr0 + rd1[reg]*wr1 + rd2[reg]*wr2;
      float o1 = sigmoidf_(z);
      o1b[rowloc*520 + gc] = f2bf(o1);
      if (t0 == 496 && rowloc == 15) O1last[b*512 + gc] = o1;
    }
  }

  f32x4 accP = {0.f,0.f,0.f,0.f};
  #pragma unroll
  for (int q2=0; q2<4; ++q2){
    int kk = w*128 + q2*32;
    short8 a2 = *(const short8*)(o1b + n16*520 + kk + g4*8);
    short8 bb2 = *(const short8*)(W2cTb + n16*512 + kk + g4*8);
    accP = __builtin_amdgcn_mfma_f32_16x16x32_bf16(a2, bb2, accP, 0,0,0);
  }
  #pragma unroll
  for (int reg=0;reg<4;++reg){
    int rowloc = g4*4+reg;
    pSum[w*256 + rowloc*16 + n16] = accP[reg];
  }
  __syncthreads();
  if (tid < 144){
    int r = tid/9, j = tid%9;
    float s = pSum[r*16+j] + pSum[256+r*16+j] + pSum[512+r*16+j] + pSum[768+r*16+j];
    float outv;
    if (j<3){ s += b2k[j]; outv = s*LOG2E; }
    else if (j<6){ s += b2w[j-3]; outv = 0.1f*s; }
    else { s += b2g[j-6]; outv = 0.1f*sigmoidf_(s); }
    P2[((long)(t0+r)*9+j)*64 + b] = outv;
  }
}

// ---------------- Kernel 4: block0 = pipelined scan2; blocks 1..64 = Opart --------------
__global__ __launch_bounds__(128) void k_scan2_opart(const float* __restrict__ P2,
    float* __restrict__ R2F,
    const float* __restrict__ O1last, const float* __restrict__ W2o,
    const float* __restrict__ b2o, float* __restrict__ Opart)
{
  if (blockIdx.x == 0){
    scan_pipelined<0>(P2, R2F);
    return;
  }
  __shared__ __align__(16) float s[512];
  int b = blockIdx.x - 1; int tid = threadIdx.x;
  float4 v = ((const float4*)(O1last + b*512))[tid];
  ((float4*)s)[tid] = v;
  __syncthreads();
  float acc = b2o[tid];
  #pragma unroll 8
  for (int n=0;n<512;++n) acc = fmaf(s[n], W2o[n*128+tid], acc);
  Opart[b*128+tid] = acc;
}

// ---------------- Kernel 5: out = sigmoid(Opart + read2 @ W2o[512:515]) -----------------
__global__ __launch_bounds__(256) void k_final(const float* __restrict__ Opart,
    const float* __restrict__ R2F, const float* __restrict__ W2o,
    float* __restrict__ out)
{
  int idx = blockIdx.x*256 + threadIdx.x;
  if (idx < 8192){
    int b = idx >> 7; int o = idx & 127;
    float r0 = R2F[b], r1 = R2F[64+b], r2 = R2F[128+b];
    float v = Opart[idx]
            + r0*W2o[512*128+o] + r1*W2o[513*128+o] + r2*W2o[514*128+o];
    out[idx] = sigmoidf_(v);
  }
}

extern "C" void kernel_launch(void* const* d_in, const int* in_sizes, int n_in,
                              void* d_out, int out_size, void* d_ws, size_t ws_size,
                              hipStream_t stream)
{
  const float* X  = (const float*)d_in[0];
  const float* W1k= (const float*)d_in[1]; const float* b1k=(const float*)d_in[2];
  const float* W1w= (const float*)d_in[3]; const float* b1w=(const float*)d_in[4];
  const float* W1g= (const float*)d_in[5]; const float* b1g=(const float*)d_in[6];
  const float* W1o= (const float*)d_in[7]; const float* b1o=(const float*)d_in[8];
  const float* W2k= (const float*)d_in[9]; const float* b2k=(const float*)d_in[10];
  const float* W2w= (const float*)d_in[11]; const float* b2w=(const float*)d_in[12];
  const float* W2g= (const float*)d_in[13]; const float* b2g=(const float*)d_in[14];
  const float* W2o= (const float*)d_in[15]; const float* b2o=(const float*)d_in[16];

  float* ws = (float*)d_ws;
  float* P1     = ws;               // 512*9*64   = 294912
  float* R1     = P1 + 294912;      // 512*3*64   =  98304
  float* P2     = R1 + 98304;      // 512*9*64   = 294912
  float* O1last = P2 + 294912;      // 64*512     =  32768
  float* R2F    = O1last + 32768;   // 3*64       =    192
  float* Opart  = R2F + 192;        // 64*128     =   8192
  unsigned short* W1oTb = (unsigned short*)(Opart + 8192);  // 512*128 bf16
  unsigned short* W2cTb = W1oTb + 65536;                    // 16*512 bf16
  float* out    = (float*)d_out;

  hipLaunchKernelGGL(k_prep, dim3(256), dim3(256), 0, stream,
                     W1o, W2k, W2w, W2g, W1oTb, W2cTb);
  hipLaunchKernelGGL(k_proj1, dim3(512), dim3(256), 0, stream,
                     X, W1k,b1k, W1w,b1w, W1g,b1g, P1);
  hipLaunchKernelGGL(k_scan1, dim3(1), dim3(128), 0, stream, P1, R1);
  hipLaunchKernelGGL(k_fused, dim3(2048), dim3(256), 0, stream,
                     X, W1o, b1o, R1, W1oTb, W2cTb, b2k, b2w, b2g, P2, O1last);
  hipLaunchKernelGGL(k_scan2_opart, dim3(65), dim3(128), 0, stream,
                     P2, R2F, O1last, W2o, b2o, Opart);
  hipLaunchKernelGGL(k_final, dim3(32), dim3(256), 0, stream,
                     Opart, R2F, W2o, out);
}

// Round 5
// 260.661 us; speedup vs baseline: 2.5363x; 1.4075x over previous
//
#include <hip/hip_runtime.h>
#include <hip/hip_bf16.h>

#define B_ 64
#define T_ 512
#define LOG2E 1.4426950408889634f
#define PHASE_STEPS 16
#define NPHASE (T_/PHASE_STEPS)

typedef __attribute__((ext_vector_type(8))) short short8;
typedef __attribute__((ext_vector_type(4))) float f32x4;

__device__ __forceinline__ float fast_exp2(float x){ return __builtin_amdgcn_exp2f(x); }
__device__ __forceinline__ float fast_rcp(float x){ return __builtin_amdgcn_rcpf(x); }
__device__ __forceinline__ float sigmoidf_(float x){ return fast_rcp(1.0f + fast_exp2(-x*LOG2E)); }
__device__ __forceinline__ unsigned short f2bf(float f){
  union{float f; unsigned u;} v; v.f = f;
  unsigned r = v.u + 0x7fffu + ((v.u>>16)&1u);
  return (unsigned short)(r>>16);
}

// DPP butterfly add over 8-lane groups (aligned): xor1, xor2, then cross-quad mirror.
template<int CTRL>
__device__ __forceinline__ float dpp_xadd(float x){
  int y = __builtin_amdgcn_update_dpp(0, __float_as_int(x), CTRL, 0xf, 0xf, true);
  return x + __int_as_float(y);
}
__device__ __forceinline__ float dpp_sum8(float x){
  x = dpp_xadd<0xB1>(x);   // quad_perm [1,0,3,2]  (xor 1)
  x = dpp_xadd<0x4E>(x);   // quad_perm [2,3,0,1]  (xor 2)
  x = dpp_xadd<0x141>(x);  // row_half_mirror      (cross-quad within 8)
  return x;
}

// ---------------- Kernel 0: prep bf16 weights -------------------------------------------
__global__ __launch_bounds__(256) void k_prep(const float* __restrict__ W1o,
    const float* __restrict__ W2k, const float* __restrict__ W2w, const float* __restrict__ W2g,
    unsigned short* __restrict__ W1oTb, unsigned short* __restrict__ W2cTb)
{
  int idx = blockIdx.x*256 + threadIdx.x;
  if (idx < 65536){
    int n = idx >> 7, k = idx & 127;
    W1oTb[idx] = f2bf(W1o[k*512 + n]);
  }
  if (idx < 8192){
    int j = idx >> 9, c = idx & 511;
    float v = 0.f;
    if (j < 3) v = W2k[c*3 + j];
    else if (j < 6) v = W2w[c*3 + j - 3];
    else if (j < 9) v = W2g[c*3 + j - 6];
    W2cTb[idx] = f2bf(v);
  }
}

// ---------------- Kernel 1: P1[bh][t][j][32] = proj of x --------------------------------
__global__ __launch_bounds__(256) void k_proj1(const float* __restrict__ X,
    const float* __restrict__ Wk, const float* __restrict__ bk,
    const float* __restrict__ Ww, const float* __restrict__ bw,
    const float* __restrict__ Wg, const float* __restrict__ bg,
    float* __restrict__ P1)
{
  __shared__ __align__(16) float A[64*132];
  __shared__ float Wc[128*12];
  __shared__ float bb[9];
  int tid = threadIdx.x;
  long r0 = (long)blockIdx.x * 64;
  const float4* X4 = (const float4*)(X + r0*128);
  #pragma unroll
  for (int it=0; it<8; ++it){
    int f4 = tid + it*256;
    float4 v = X4[f4];
    int f = f4*4; int row = f>>7; int k = f&127;
    A[row*132+k]   = v.x; A[row*132+k+1] = v.y;
    A[row*132+k+2] = v.z; A[row*132+k+3] = v.w;
  }
  #pragma unroll
  for (int it=0; it<5; ++it){
    int w = tid + it*256;
    if (w < 1152){
      int k = w/9, j = w%9;
      float val;
      if (j<3) val = Wk[k*3+j]; else if (j<6) val = Ww[k*3+j-3]; else val = Wg[k*3+j-6];
      Wc[k*12+j] = val;
    }
  }
  if (tid < 9){
    float v; if (tid<3) v = bk[tid]; else if (tid<6) v = bw[tid-3]; else v = bg[tid-6];
    bb[tid] = v;
  }
  __syncthreads();
  for (int o = tid; o < 576; o += 256){
    int row = o/9, j = o%9;
    float acc = bb[j];
    #pragma unroll 8
    for (int k=0;k<128;++k) acc = fmaf(A[row*132+k], Wc[k*12+j], acc);
    if (j<3) acc *= LOG2E;
    else if (j<6) acc *= 0.1f;
    else acc = 0.1f * sigmoidf_(acc);
    long r = r0 + row;
    int b = (int)(r >> 9); int t = (int)(r & 511);
    int bh = b >> 5, bl = b & 31;
    P1[((long)bh*512 + t)*288 + j*32 + bl] = acc;
  }
}

// ---------------- parallel-slot scan ----------------------------------------------------
// Block = 320 threads: waves 0..3 compute (8 batches x 8 slots per wave), wave 4 = DMA.
// P slice for block bh is contiguous: [512][9][32] floats. Double-buffered 16-step phases.
template<int STORE_ALL>
__device__ __forceinline__ void scan8(const float* __restrict__ P,
                                      float* __restrict__ Rout, int bh)
{
  __shared__ __align__(16) float buf[2][PHASE_STEPS*288];
  int tid = threadIdx.x;
  int wv = tid >> 6, lane = tid & 63;
  const float* Pb = P + (long)bh*512*288;
  if (wv == 4){
    #pragma unroll 1
    for (int p = 0; p < NPHASE; ++p){
      const float4* src = (const float4*)(Pb + (long)p*PHASE_STEPS*288);
      float4* dst = (float4*)buf[p&1];
      float4 tmp[18];
      #pragma unroll
      for (int i=0;i<18;++i) tmp[i] = src[lane + i*64];
      #pragma unroll
      for (int i=0;i<18;++i) dst[lane + i*64] = tmp[i];
      __syncthreads();
    }
  } else {
    int g = lane >> 3, slot = lane & 7;
    int bl = wv*8 + g;
    int batch = bh*32 + bl;
    float m0=0.f, m1=0.f, m2=0.f;
    __syncthreads();  // buf0 ready
    #pragma unroll 1
    for (int p = 0; p < NPHASE; ++p){
      const float* bp = buf[p&1];
      float pp[3][9];
      #pragma unroll
      for (int j=0;j<9;++j){ pp[0][j] = bp[j*32+bl]; pp[1][j] = bp[288 + j*32+bl]; }
      #pragma unroll
      for (int s=0;s<PHASE_STEPS;++s){
        if (s+2 < PHASE_STEPS){
          #pragma unroll
          for (int j=0;j<9;++j) pp[(s+2)%3][j] = bp[(s+2)*288 + j*32 + bl];
        }
        const float* pv = pp[s%3];
        float sc = fmaf(m2, pv[2], fmaf(m1, pv[1], m0*pv[0]));
        float pe = fast_exp2(sc);
        float S = dpp_sum8(pe);
        float rinv = fast_rcp(S);
        float w = pe * rinv;
        if (STORE_ALL){
          float r0 = dpp_sum8(pe*m0);
          float r1 = dpp_sum8(pe*m1);
          float r2 = dpp_sum8(pe*m2);
          float rsel = (slot==0) ? r0 : ((slot==1) ? r1 : r2);
          rsel *= rinv;
          if (slot < 3) Rout[((p*PHASE_STEPS+s)*3 + slot)*64 + batch] = rsel;
        } else if (s == PHASE_STEPS-1){
          if (p == NPHASE-1){
            float r0 = dpp_sum8(pe*m0);
            float r1 = dpp_sum8(pe*m1);
            float r2 = dpp_sum8(pe*m2);
            float rsel = (slot==0) ? r0 : ((slot==1) ? r1 : r2);
            rsel *= rinv;
            if (slot < 3) Rout[slot*64 + batch] = rsel;
          }
        }
        float v0=pv[3], v1=pv[4], v2=pv[5], e0=pv[6], e1=pv[7], e2=pv[8];
        m0 = fmaf(w, fmaf(-e0, m0, v0), m0);
        m1 = fmaf(w, fmaf(-e1, m1, v1), m1);
        m2 = fmaf(w, fmaf(-e2, m2, v2), m2);
      }
      if (p < NPHASE-1) __syncthreads();
    }
  }
}

__global__ __launch_bounds__(320) void k_scan1(const float* __restrict__ P1,
                                               float* __restrict__ R1)
{
  scan8<1>(P1, R1, (int)blockIdx.x);
}

// ---------------- Kernel 3: MFMA fused z1=x@W1o, o1=sigmoid(.), P2=o1@W2c ---------------
__global__ __launch_bounds__(256) void k_fused(const float* __restrict__ X,
    const float* __restrict__ W1o, const float* __restrict__ b1o,
    const float* __restrict__ R1,
    const unsigned short* __restrict__ W1oTb, const unsigned short* __restrict__ W2cTb,
    const float* __restrict__ b2k, const float* __restrict__ b2w, const float* __restrict__ b2g,
    float* __restrict__ P2, float* __restrict__ O1last)
{
  __shared__ __align__(16) float rdS[48];
  __shared__ __align__(16) unsigned short o1b[16*520];
  __shared__ __align__(16) float pSum[4*16*16];
  int tid = threadIdx.x;
  int w = tid >> 6, lane = tid & 63;
  int n16 = lane & 15, g4 = lane >> 4;
  long r0 = (long)blockIdx.x * 16;
  int b = (int)(r0 >> 9); int t0 = (int)(r0 & 511);

  if (tid < 48){
    int i = tid/3, d = tid%3;
    rdS[tid] = R1[((t0+i)*3+d)*64 + b];
  }

  short8 afr[4];
  const float* Xrow = X + (r0 + n16)*128;
  #pragma unroll
  for (int q=0;q<4;++q){
    f32x4 x0 = *(const f32x4*)(Xrow + q*32 + g4*8);
    f32x4 x1 = *(const f32x4*)(Xrow + q*32 + g4*8 + 4);
    short8 a;
    a[0]=(short)f2bf(x0[0]); a[1]=(short)f2bf(x0[1]);
    a[2]=(short)f2bf(x0[2]); a[3]=(short)f2bf(x0[3]);
    a[4]=(short)f2bf(x1[0]); a[5]=(short)f2bf(x1[1]);
    a[6]=(short)f2bf(x1[2]); a[7]=(short)f2bf(x1[3]);
    afr[q]=a;
  }
  __syncthreads();

  f32x4 ra = *(const f32x4*)(rdS + g4*12);
  f32x4 rb = *(const f32x4*)(rdS + g4*12 + 4);
  f32x4 rc = *(const f32x4*)(rdS + g4*12 + 8);
  float rd0[4] = { ra[0], ra[3], rb[2], rc[1] };
  float rd1[4] = { ra[1], rb[0], rb[3], rc[2] };
  float rd2[4] = { ra[2], rb[1], rc[0], rc[3] };

  #pragma unroll
  for (int tt=0; tt<8; ++tt){
    int gc = w*128 + tt*16 + n16;
    f32x4 acc = {0.f,0.f,0.f,0.f};
    #pragma unroll
    for (int q=0;q<4;++q){
      short8 bf = *(const short8*)(W1oTb + gc*128 + q*32 + g4*8);
      acc = __builtin_amdgcn_mfma_f32_16x16x32_bf16(afr[q], bf, acc, 0,0,0);
    }
    float bias = b1o[gc];
    float wr0 = W1o[128*512+gc], wr1 = W1o[129*512+gc], wr2 = W1o[130*512+gc];
    #pragma unroll
    for (int reg=0; reg<4; ++reg){
      int rowloc = g4*4 + reg;
      float z = acc[reg] + bias + rd0[reg]*wr0 + rd1[reg]*wr1 + rd2[reg]*wr2;
      float o1 = sigmoidf_(z);
      o1b[rowloc*520 + gc] = f2bf(o1);
      if (t0 == 496 && rowloc == 15) O1last[b*512 + gc] = o1;
    }
  }

  f32x4 accP = {0.f,0.f,0.f,0.f};
  #pragma unroll
  for (int q2=0; q2<4; ++q2){
    int kk = w*128 + q2*32;
    short8 a2 = *(const short8*)(o1b + n16*520 + kk + g4*8);
    short8 bb2 = *(const short8*)(W2cTb + n16*512 + kk + g4*8);
    accP = __builtin_amdgcn_mfma_f32_16x16x32_bf16(a2, bb2, accP, 0,0,0);
  }
  #pragma unroll
  for (int reg=0;reg<4;++reg){
    int rowloc = g4*4+reg;
    pSum[w*256 + rowloc*16 + n16] = accP[reg];
  }
  __syncthreads();
  if (tid < 144){
    int r = tid/9, j = tid%9;
    float s = pSum[r*16+j] + pSum[256+r*16+j] + pSum[512+r*16+j] + pSum[768+r*16+j];
    float outv;
    if (j<3){ s += b2k[j]; outv = s*LOG2E; }
    else if (j<6){ s += b2w[j-3]; outv = 0.1f*s; }
    else { s += b2g[j-6]; outv = 0.1f*sigmoidf_(s); }
    int t = t0 + r;
    int bh = b >> 5, bl = b & 31;
    P2[((long)bh*512 + t)*288 + j*32 + bl] = outv;
  }
}

// ---------------- Kernel 4: blocks 0,1 = scan2; blocks 2..65 = Opart --------------------
__global__ __launch_bounds__(320) void k_scan2_opart(const float* __restrict__ P2,
    float* __restrict__ R2F,
    const float* __restrict__ O1last, const float* __restrict__ W2o,
    const float* __restrict__ b2o, float* __restrict__ Opart)
{
  if (blockIdx.x < 2){
    scan8<0>(P2, R2F, (int)blockIdx.x);
    return;
  }
  __shared__ __align__(16) float s2[512];
  int b = blockIdx.x - 2; int tid = threadIdx.x;
  if (tid < 128)
    ((float4*)s2)[tid] = ((const float4*)(O1last + b*512))[tid];
  __syncthreads();
  if (tid < 128){
    float acc = b2o[tid];
    #pragma unroll 8
    for (int n=0;n<512;++n) acc = fmaf(s2[n], W2o[n*128+tid], acc);
    Opart[b*128+tid] = acc;
  }
}

// ---------------- Kernel 5: out = sigmoid(Opart + read2 @ W2o[512:515]) -----------------
__global__ __launch_bounds__(256) void k_final(const float* __restrict__ Opart,
    const float* __restrict__ R2F, const float* __restrict__ W2o,
    float* __restrict__ out)
{
  int idx = blockIdx.x*256 + threadIdx.x;
  if (idx < 8192){
    int b = idx >> 7; int o = idx & 127;
    float r0 = R2F[b], r1 = R2F[64+b], r2 = R2F[128+b];
    float v = Opart[idx]
            + r0*W2o[512*128+o] + r1*W2o[513*128+o] + r2*W2o[514*128+o];
    out[idx] = sigmoidf_(v);
  }
}

extern "C" void kernel_launch(void* const* d_in, const int* in_sizes, int n_in,
                              void* d_out, int out_size, void* d_ws, size_t ws_size,
                              hipStream_t stream)
{
  const float* X  = (const float*)d_in[0];
  const float* W1k= (const float*)d_in[1]; const float* b1k=(const float*)d_in[2];
  const float* W1w= (const float*)d_in[3]; const float* b1w=(const float*)d_in[4];
  const float* W1g= (const float*)d_in[5]; const float* b1g=(const float*)d_in[6];
  const float* W1o= (const float*)d_in[7]; const float* b1o=(const float*)d_in[8];
  const float* W2k= (const float*)d_in[9]; const float* b2k=(const float*)d_in[10];
  const float* W2w= (const float*)d_in[11]; const float* b2w=(const float*)d_in[12];
  const float* W2g= (const float*)d_in[13]; const float* b2g=(const float*)d_in[14];
  const float* W2o= (const float*)d_in[15]; const float* b2o=(const float*)d_in[16];

  float* ws = (float*)d_ws;
  float* P1     = ws;               // 2*512*288  = 294912
  float* R1     = P1 + 294912;      // 512*3*64   =  98304
  float* P2     = R1 + 98304;       // 2*512*288  = 294912
  float* O1last = P2 + 294912;      // 64*512     =  32768
  float* R2F    = O1last + 32768;   // 3*64       =    192
  float* Opart  = R2F + 192;        // 64*128     =   8192
  unsigned short* W1oTb = (unsigned short*)(Opart + 8192);  // 512*128 bf16
  unsigned short* W2cTb = W1oTb + 65536;                    // 16*512 bf16
  float* out    = (float*)d_out;

  hipLaunchKernelGGL(k_prep, dim3(256), dim3(256), 0, stream,
                     W1o, W2k, W2w, W2g, W1oTb, W2cTb);
  hipLaunchKernelGGL(k_proj1, dim3(512), dim3(256), 0, stream,
                     X, W1k,b1k, W1w,b1w, W1g,b1g, P1);
  hipLaunchKernelGGL(k_scan1, dim3(2), dim3(320), 0, stream, P1, R1);
  hipLaunchKernelGGL(k_fused, dim3(2048), dim3(256), 0, stream,
                     X, W1o, b1o, R1, W1oTb, W2cTb, b2k, b2w, b2g, P2, O1last);
  hipLaunchKernelGGL(k_scan2_opart, dim3(66), dim3(320), 0, stream,
                     P2, R2F, O1last, W2o, b2o, Opart);
  hipLaunchKernelGGL(k_final, dim3(32), dim3(256), 0, stream,
                     Opart, R2F, W2o, out);
}